// Round 1
// baseline (1226.096 us; speedup 1.0000x reference)
//
#include <hip/hip_runtime.h>

#define HID 128
#define NLAYERS 4

// ---------------- utility kernels ----------------

__global__ void zero_i32(int* p, int n) {
    int i = blockIdx.x * blockDim.x + threadIdx.x;
    if (i < n) p[i] = 0;
}

__global__ void hist_kernel(const int* __restrict__ dst, int* __restrict__ cnt, int E) {
    int e = blockIdx.x * blockDim.x + threadIdx.x;
    if (e < E) atomicAdd(&cnt[dst[e]], 1);
}

__global__ void dis_kernel(const int* __restrict__ cnt, float* __restrict__ dis, int n) {
    int i = blockIdx.x * blockDim.x + threadIdx.x;
    if (i < n) dis[i] = rsqrtf((float)cnt[i] + 1.0f);
}

// exclusive scan of cnt[0..n) -> rowp, per-block partials to bsums
__global__ void scan1(const int* __restrict__ cnt, int* __restrict__ rowp,
                      int* __restrict__ bsums, int n) {
    __shared__ int s[1024];
    int tid = threadIdx.x;
    int gid = blockIdx.x * 1024 + tid;
    int v = (gid < n) ? cnt[gid] : 0;
    s[tid] = v;
    __syncthreads();
    for (int off = 1; off < 1024; off <<= 1) {
        int t = (tid >= off) ? s[tid - off] : 0;
        __syncthreads();
        s[tid] += t;
        __syncthreads();
    }
    if (gid < n) rowp[gid] = s[tid] - v;   // exclusive
    if (tid == 1023) bsums[blockIdx.x] = s[1023];
}

__global__ void scan2(int* bsums, int nb) {
    if (threadIdx.x == 0 && blockIdx.x == 0) {
        int run = 0;
        for (int i = 0; i < nb; ++i) { int t = bsums[i]; bsums[i] = run; run += t; }
    }
}

__global__ void scan3(int* __restrict__ rowp, const int* __restrict__ bsums, int n, int E) {
    int gid = blockIdx.x * 1024 + threadIdx.x;
    if (gid < n) rowp[gid] += bsums[blockIdx.x];
    if (gid == 0) rowp[n] = E;
}

// fill CSR: for each edge, pos = rowp[dst] + cursor++; store packed (src, dis[src])
__global__ void scatter_kernel(const int* __restrict__ src, const int* __restrict__ dst,
                               const int* __restrict__ rowp, int* __restrict__ cursor,
                               const float* __restrict__ dis, int2* __restrict__ csr, int E) {
    int e = blockIdx.x * blockDim.x + threadIdx.x;
    if (e < E) {
        int d = dst[e], s = src[e];
        int pos = rowp[d] + atomicAdd(&cursor[d], 1);
        int2 v;
        v.x = s;
        v.y = __float_as_int(dis[s]);
        csr[pos] = v;
    }
}

// zsum = c * Z   (vectorized)
__global__ void scalecopy(const float4* __restrict__ Z, float4* __restrict__ zsum, int n4, float c) {
    int i = blockIdx.x * blockDim.x + threadIdx.x;
    if (i < n4) {
        float4 v = Z[i];
        v.x *= c; v.y *= c; v.z *= c; v.w *= c;
        zsum[i] = v;
    }
}

// ---------------- GEMM: C[n,OUTD] = scaleA * A[n,128] @ W[128,OUTD] (+bias) ----------------

template <int OUTD>
__global__ __launch_bounds__(256) void gemm_k128(
    const float* __restrict__ A, const float* __restrict__ W,
    const float* __restrict__ bias, float* __restrict__ C,
    int nrows, float scaleA) {
    constexpr int ROWS = 4096 / OUTD;   // 32 (OUTD=128) or 64 (OUTD=64)
    constexpr int CG = OUTD / 4;        // float4 col groups per row
    __shared__ float Wl[HID][OUTD];
    __shared__ float Al[ROWS][HID];

    int tid = threadIdx.x;
    // stage W (whole matrix)
    for (int i = tid; i < HID * CG; i += 256) {
        int r = i / CG, c = i % CG;
        *(float4*)&Wl[r][c * 4] = *(const float4*)&W[(size_t)r * OUTD + c * 4];
    }
    // stage A tile
    int row0g = blockIdx.x * ROWS;
    for (int i = tid; i < ROWS * 32; i += 256) {
        int r = i / 32, c = i % 32;
        int gr = row0g + r;
        float4 v = make_float4(0.f, 0.f, 0.f, 0.f);
        if (gr < nrows) v = *(const float4*)&A[(size_t)gr * HID + c * 4];
        *(float4*)&Al[r][c * 4] = v;
    }
    __syncthreads();

    int cg = tid % CG, rg = tid / CG;
    int c0 = cg * 4, r0 = rg * 4;
    float acc[4][4] = {};

#pragma unroll 4
    for (int k = 0; k < HID; ++k) {
        float4 w4 = *(float4*)&Wl[k][c0];
        float a0 = Al[r0 + 0][k];
        float a1 = Al[r0 + 1][k];
        float a2 = Al[r0 + 2][k];
        float a3 = Al[r0 + 3][k];
        acc[0][0] = fmaf(a0, w4.x, acc[0][0]); acc[0][1] = fmaf(a0, w4.y, acc[0][1]);
        acc[0][2] = fmaf(a0, w4.z, acc[0][2]); acc[0][3] = fmaf(a0, w4.w, acc[0][3]);
        acc[1][0] = fmaf(a1, w4.x, acc[1][0]); acc[1][1] = fmaf(a1, w4.y, acc[1][1]);
        acc[1][2] = fmaf(a1, w4.z, acc[1][2]); acc[1][3] = fmaf(a1, w4.w, acc[1][3]);
        acc[2][0] = fmaf(a2, w4.x, acc[2][0]); acc[2][1] = fmaf(a2, w4.y, acc[2][1]);
        acc[2][2] = fmaf(a2, w4.z, acc[2][2]); acc[2][3] = fmaf(a2, w4.w, acc[2][3]);
        acc[3][0] = fmaf(a3, w4.x, acc[3][0]); acc[3][1] = fmaf(a3, w4.y, acc[3][1]);
        acc[3][2] = fmaf(a3, w4.z, acc[3][2]); acc[3][3] = fmaf(a3, w4.w, acc[3][3]);
    }

    float bx = 0.f, by = 0.f, bz = 0.f, bw = 0.f;
    if (bias) { bx = bias[c0]; by = bias[c0 + 1]; bz = bias[c0 + 2]; bw = bias[c0 + 3]; }
#pragma unroll
    for (int j = 0; j < 4; ++j) {
        int gr = row0g + r0 + j;
        if (gr < nrows) {
            float4 o;
            o.x = fmaf(acc[j][0], scaleA, bx);
            o.y = fmaf(acc[j][1], scaleA, by);
            o.z = fmaf(acc[j][2], scaleA, bz);
            o.w = fmaf(acc[j][3], scaleA, bw);
            *(float4*)&C[(size_t)gr * OUTD + c0] = o;
        }
    }
}

// ---------------- fused SpMM + self-loop + bias + ReLU + z_sum ----------------
// 32 lanes per node, float4 per lane (128 cols). 8 nodes per 256-thread block.

__global__ __launch_bounds__(256) void spmm_kernel(
    const float* __restrict__ xw, const int* __restrict__ rowp,
    const int2* __restrict__ csr, const float* __restrict__ dis,
    const float* __restrict__ bias, float* __restrict__ Znew,
    float* __restrict__ zsum, int n) {
    int lane = threadIdx.x & 31;
    int node = blockIdx.x * 8 + (threadIdx.x >> 5);
    if (node >= n) return;
    const float4* xw4 = (const float4*)xw;

    float4 acc = make_float4(0.f, 0.f, 0.f, 0.f);
    int beg = rowp[node], end = rowp[node + 1];
    for (int e = beg; e < end; ++e) {
        int2 sw = csr[e];                       // uniform across the 32-lane group
        float w = __int_as_float(sw.y);
        float4 xv = xw4[(size_t)sw.x * 32 + lane];
        acc.x = fmaf(w, xv.x, acc.x);
        acc.y = fmaf(w, xv.y, acc.y);
        acc.z = fmaf(w, xv.z, acc.z);
        acc.w = fmaf(w, xv.w, acc.w);
    }
    float d = dis[node];
    float d2 = d * d;
    size_t o = (size_t)node * 32 + lane;
    float4 xs = xw4[o];
    float4 b = ((const float4*)bias)[lane];
    float4 v;
    v.x = fmaxf(fmaf(d, acc.x, fmaf(d2, xs.x, b.x)), 0.f);
    v.y = fmaxf(fmaf(d, acc.y, fmaf(d2, xs.y, b.y)), 0.f);
    v.z = fmaxf(fmaf(d, acc.z, fmaf(d2, xs.z, b.z)), 0.f);
    v.w = fmaxf(fmaf(d, acc.w, fmaf(d2, xs.w, b.w)), 0.f);
    ((float4*)Znew)[o] = v;
    float4 zs = ((float4*)zsum)[o];
    zs.x += v.x; zs.y += v.y; zs.z += v.z; zs.w += v.w;
    ((float4*)zsum)[o] = zs;
}

// ---------------- launcher ----------------

extern "C" void kernel_launch(void* const* d_in, const int* in_sizes, int n_in,
                              void* d_out, int out_size, void* d_ws, size_t ws_size,
                              hipStream_t stream) {
    const float* x     = (const float*)d_in[0];
    const int*   ei    = (const int*)d_in[1];
    const float* W1    = (const float*)d_in[2];
    const float* b1    = (const float*)d_in[3];
    const float* convW = (const float*)d_in[4];
    const float* convB = (const float*)d_in[5];
    const float* W2    = (const float*)d_in[6];
    const float* b2    = (const float*)d_in[7];

    const int N = in_sizes[0] / HID;
    const int E = in_sizes[1] / 2;
    const int* src = ei;
    const int* dst = ei + E;

    char* p = (char*)d_ws;
    auto alloc = [&](size_t bytes) {
        void* q = (void*)p;
        p += (bytes + 255) & ~(size_t)255;
        return q;
    };
    float* dis   = (float*)alloc((size_t)N * 4);
    int*   cnt   = (int*)alloc((size_t)N * 4);
    int*   rowp  = (int*)alloc((size_t)(N + 1) * 4);
    int*   bsums = (int*)alloc(4096);
    int2*  csr   = (int2*)alloc((size_t)E * 8);
    float* Z     = (float*)alloc((size_t)N * HID * 4);
    float* xw    = (float*)alloc((size_t)N * HID * 4);
    float* zsum  = (float*)alloc((size_t)N * HID * 4);

    const int nb = (N + 1023) / 1024;

    // --- graph preprocessing: degrees + CSR by dst ---
    zero_i32<<<(N + 255) / 256, 256, 0, stream>>>(cnt, N);
    hist_kernel<<<(E + 255) / 256, 256, 0, stream>>>(dst, cnt, E);
    dis_kernel<<<(N + 255) / 256, 256, 0, stream>>>(cnt, dis, N);
    scan1<<<nb, 1024, 0, stream>>>(cnt, rowp, bsums, N);
    scan2<<<1, 64, 0, stream>>>(bsums, nb);
    scan3<<<nb, 1024, 0, stream>>>(rowp, bsums, N, E);
    zero_i32<<<(N + 255) / 256, 256, 0, stream>>>(cnt, N);
    scatter_kernel<<<(E + 255) / 256, 256, 0, stream>>>(src, dst, rowp, cnt, dis, csr, E);

    // --- Z = x@W1 + b1 ; zsum = 6*Z  (folds ALPHA*z_init) ---
    gemm_k128<128><<<(N + 31) / 32, 256, 0, stream>>>(x, W1, b1, Z, N, 1.f);
    scalecopy<<<(N * 32 + 255) / 256, 256, 0, stream>>>((const float4*)Z, (float4*)zsum, N * 32, 6.f);

    // --- 4 GCN layers ---
    for (int l = 0; l < NLAYERS; ++l) {
        gemm_k128<128><<<(N + 31) / 32, 256, 0, stream>>>(
            Z, convW + (size_t)l * HID * HID, nullptr, xw, N, 1.f);
        spmm_kernel<<<(N + 7) / 8, 256, 0, stream>>>(
            xw, rowp, csr, dis, convB + (size_t)l * HID, Z, zsum, N);
    }

    // --- out = (0.1*zsum) @ W2 + b2 ---
    gemm_k128<64><<<(N + 63) / 64, 256, 0, stream>>>(zsum, W2, b2, (float*)d_out, N, 0.1f);
}

// Round 2
// 965.914 us; speedup vs baseline: 1.2694x; 1.2694x over previous
//
#include <hip/hip_runtime.h>

#define HID 128
#define NLAYERS 4

typedef unsigned short ushort8 __attribute__((ext_vector_type(8)));

static __device__ __forceinline__ float bf2f(unsigned short u) {
    return __uint_as_float(((unsigned)u) << 16);
}
static __device__ __forceinline__ unsigned short f2bf(float f) {
    unsigned u = __float_as_uint(f);
    unsigned r = (u + 0x7FFF + ((u >> 16) & 1)) >> 16;   // RNE
    return (unsigned short)r;
}

// ---------------- utility kernels ----------------

__global__ void zero_i32(int* p, int n) {
    int i = blockIdx.x * blockDim.x + threadIdx.x;
    if (i < n) p[i] = 0;
}

__global__ void hist_kernel(const int* __restrict__ dst, int* __restrict__ cnt, int E) {
    int e = blockIdx.x * blockDim.x + threadIdx.x;
    if (e < E) atomicAdd(&cnt[dst[e]], 1);
}

__global__ void dis_kernel(const int* __restrict__ cnt, float* __restrict__ dis, int n) {
    int i = blockIdx.x * blockDim.x + threadIdx.x;
    if (i < n) dis[i] = rsqrtf((float)cnt[i] + 1.0f);
}

__global__ void scan1(const int* __restrict__ cnt, int* __restrict__ rowp,
                      int* __restrict__ bsums, int n) {
    __shared__ int s[1024];
    int tid = threadIdx.x;
    int gid = blockIdx.x * 1024 + tid;
    int v = (gid < n) ? cnt[gid] : 0;
    s[tid] = v;
    __syncthreads();
    for (int off = 1; off < 1024; off <<= 1) {
        int t = (tid >= off) ? s[tid - off] : 0;
        __syncthreads();
        s[tid] += t;
        __syncthreads();
    }
    if (gid < n) rowp[gid] = s[tid] - v;   // exclusive
    if (tid == 1023) bsums[blockIdx.x] = s[1023];
}

__global__ void scan2(int* bsums, int nb) {
    if (threadIdx.x == 0 && blockIdx.x == 0) {
        int run = 0;
        for (int i = 0; i < nb; ++i) { int t = bsums[i]; bsums[i] = run; run += t; }
    }
}

__global__ void scan3(int* __restrict__ rowp, const int* __restrict__ bsums, int n, int E) {
    int gid = blockIdx.x * 1024 + threadIdx.x;
    if (gid < n) rowp[gid] += bsums[blockIdx.x];
    if (gid == 0) rowp[n] = E;
}

__global__ void scatter_kernel(const int* __restrict__ src, const int* __restrict__ dst,
                               const int* __restrict__ rowp, int* __restrict__ cursor,
                               const float* __restrict__ dis, int2* __restrict__ csr, int E) {
    int e = blockIdx.x * blockDim.x + threadIdx.x;
    if (e < E) {
        int d = dst[e], s = src[e];
        int pos = rowp[d] + atomicAdd(&cursor[d], 1);
        int2 v;
        v.x = s;
        v.y = __float_as_int(dis[s]);
        csr[pos] = v;
    }
}

// ---------------- GEMM: C[n,OUTD] = scaleA * Aeff[n,128] @ W[128,OUTD] (+bias) ----------
// ZMODE: 0 none, 1 zsum = 6*C (write-only), 2 zsum += A (RMW from staged LDS tile)
// ADD2:  Aeff = A + A2 (two-stream read)
// BF16OUT: C stored as bf16

template <int OUTD, int ZMODE, bool ADD2, bool BF16OUT>
__global__ __launch_bounds__(256) void gemm_k128(
    const float* __restrict__ A, const float* __restrict__ A2,
    const float* __restrict__ W, const float* __restrict__ bias,
    void* __restrict__ Cout, float* __restrict__ zsum,
    int nrows, float scaleA) {
    constexpr int ROWS = 4096 / OUTD;   // 32 (OUTD=128) or 64 (OUTD=64)
    constexpr int CG = OUTD / 4;
    __shared__ float Wl[HID][OUTD];
    __shared__ float Al[ROWS][HID];

    int tid = threadIdx.x;
    for (int i = tid; i < HID * CG; i += 256) {
        int r = i / CG, c = i % CG;
        *(float4*)&Wl[r][c * 4] = *(const float4*)&W[(size_t)r * OUTD + c * 4];
    }
    int row0g = blockIdx.x * ROWS;
    for (int i = tid; i < ROWS * 32; i += 256) {
        int r = i / 32, c = i % 32;
        int gr = row0g + r;
        float4 v = make_float4(0.f, 0.f, 0.f, 0.f);
        if (gr < nrows) {
            v = *(const float4*)&A[(size_t)gr * HID + c * 4];
            if (ADD2) {
                float4 v2 = *(const float4*)&A2[(size_t)gr * HID + c * 4];
                v.x += v2.x; v.y += v2.y; v.z += v2.z; v.w += v2.w;
            }
        }
        *(float4*)&Al[r][c * 4] = v;
    }
    __syncthreads();

    int cg = tid % CG, rg = tid / CG;
    int c0 = cg * 4, r0 = rg * 4;
    float acc[4][4] = {};

#pragma unroll 4
    for (int k = 0; k < HID; ++k) {
        float4 w4 = *(float4*)&Wl[k][c0];
        float a0 = Al[r0 + 0][k];
        float a1 = Al[r0 + 1][k];
        float a2 = Al[r0 + 2][k];
        float a3 = Al[r0 + 3][k];
        acc[0][0] = fmaf(a0, w4.x, acc[0][0]); acc[0][1] = fmaf(a0, w4.y, acc[0][1]);
        acc[0][2] = fmaf(a0, w4.z, acc[0][2]); acc[0][3] = fmaf(a0, w4.w, acc[0][3]);
        acc[1][0] = fmaf(a1, w4.x, acc[1][0]); acc[1][1] = fmaf(a1, w4.y, acc[1][1]);
        acc[1][2] = fmaf(a1, w4.z, acc[1][2]); acc[1][3] = fmaf(a1, w4.w, acc[1][3]);
        acc[2][0] = fmaf(a2, w4.x, acc[2][0]); acc[2][1] = fmaf(a2, w4.y, acc[2][1]);
        acc[2][2] = fmaf(a2, w4.z, acc[2][2]); acc[2][3] = fmaf(a2, w4.w, acc[2][3]);
        acc[3][0] = fmaf(a3, w4.x, acc[3][0]); acc[3][1] = fmaf(a3, w4.y, acc[3][1]);
        acc[3][2] = fmaf(a3, w4.z, acc[3][2]); acc[3][3] = fmaf(a3, w4.w, acc[3][3]);
    }

    if (ZMODE == 2) {
        // zsum += A rows (A tile already staged in LDS, each global row visited once)
        for (int i = tid; i < ROWS * 32; i += 256) {
            int r = i / 32, c = i % 32;
            int gr = row0g + r;
            if (gr < nrows) {
                float4 z = *(float4*)&zsum[(size_t)gr * HID + c * 4];
                float4 a = *(float4*)&Al[r][c * 4];
                z.x += a.x; z.y += a.y; z.z += a.z; z.w += a.w;
                *(float4*)&zsum[(size_t)gr * HID + c * 4] = z;
            }
        }
    }

    float bx = 0.f, by = 0.f, bz = 0.f, bw = 0.f;
    if (bias) { bx = bias[c0]; by = bias[c0 + 1]; bz = bias[c0 + 2]; bw = bias[c0 + 3]; }
#pragma unroll
    for (int j = 0; j < 4; ++j) {
        int gr = row0g + r0 + j;
        if (gr < nrows) {
            float4 o;
            o.x = fmaf(acc[j][0], scaleA, bx);
            o.y = fmaf(acc[j][1], scaleA, by);
            o.z = fmaf(acc[j][2], scaleA, bz);
            o.w = fmaf(acc[j][3], scaleA, bw);
            if (BF16OUT) {
                unsigned short p[4] = { f2bf(o.x), f2bf(o.y), f2bf(o.z), f2bf(o.w) };
                *(uint2*)((unsigned short*)Cout + (size_t)gr * OUTD + c0) = *(uint2*)p;
            } else {
                *(float4*)((float*)Cout + (size_t)gr * OUTD + c0) = o;
            }
            if (ZMODE == 1) {
                float4 z;
                z.x = 6.f * o.x; z.y = 6.f * o.y; z.z = 6.f * o.z; z.w = 6.f * o.w;
                *(float4*)&zsum[(size_t)gr * HID + c0] = z;
            }
        }
    }
}

// ---------------- fused SpMM(bf16 gather) + self-loop + bias + ReLU ----------------
// 16 lanes per node, ushort8 (16B) per lane. 16 nodes per 256-thread block.

__global__ __launch_bounds__(256) void spmm_kernel(
    const unsigned short* __restrict__ xwb, const int* __restrict__ rowp,
    const int2* __restrict__ csr, const float* __restrict__ dis,
    const float* __restrict__ bias, float* __restrict__ Z, int n) {
    int l = threadIdx.x & 15;
    int node = blockIdx.x * 16 + (threadIdx.x >> 4);
    if (node >= n) return;
    const ushort8* xw8 = (const ushort8*)xwb;   // 16 ushort8 per row

    float acc[8] = {};
    int beg = rowp[node], end = rowp[node + 1];
    int e = beg;
    for (; e + 1 < end; e += 2) {
        int2 s0 = csr[e];
        int2 s1 = csr[e + 1];
        ushort8 x0 = xw8[(size_t)s0.x * 16 + l];
        ushort8 x1 = xw8[(size_t)s1.x * 16 + l];
        float w0 = __int_as_float(s0.y);
        float w1 = __int_as_float(s1.y);
#pragma unroll
        for (int j = 0; j < 8; ++j) acc[j] = fmaf(w0, bf2f(x0[j]), acc[j]);
#pragma unroll
        for (int j = 0; j < 8; ++j) acc[j] = fmaf(w1, bf2f(x1[j]), acc[j]);
    }
    if (e < end) {
        int2 s0 = csr[e];
        ushort8 x0 = xw8[(size_t)s0.x * 16 + l];
        float w0 = __int_as_float(s0.y);
#pragma unroll
        for (int j = 0; j < 8; ++j) acc[j] = fmaf(w0, bf2f(x0[j]), acc[j]);
    }

    float d = dis[node];
    float d2 = d * d;
    ushort8 xs = xw8[(size_t)node * 16 + l];
    float4 b0 = *(const float4*)&bias[l * 8];
    float4 b1 = *(const float4*)&bias[l * 8 + 4];
    float bb[8] = { b0.x, b0.y, b0.z, b0.w, b1.x, b1.y, b1.z, b1.w };
    float v[8];
#pragma unroll
    for (int j = 0; j < 8; ++j)
        v[j] = fmaxf(fmaf(d, acc[j], fmaf(d2, bf2f(xs[j]), bb[j])), 0.f);
    float* zp = &Z[(size_t)node * HID + l * 8];
    *(float4*)zp = make_float4(v[0], v[1], v[2], v[3]);
    *(float4*)(zp + 4) = make_float4(v[4], v[5], v[6], v[7]);
}

// ---------------- launcher ----------------

extern "C" void kernel_launch(void* const* d_in, const int* in_sizes, int n_in,
                              void* d_out, int out_size, void* d_ws, size_t ws_size,
                              hipStream_t stream) {
    const float* x     = (const float*)d_in[0];
    const int*   ei    = (const int*)d_in[1];
    const float* W1    = (const float*)d_in[2];
    const float* b1    = (const float*)d_in[3];
    const float* convW = (const float*)d_in[4];
    const float* convB = (const float*)d_in[5];
    const float* W2    = (const float*)d_in[6];
    const float* b2    = (const float*)d_in[7];

    const int N = in_sizes[0] / HID;
    const int E = in_sizes[1] / 2;
    const int* src = ei;
    const int* dst = ei + E;

    char* p = (char*)d_ws;
    auto alloc = [&](size_t bytes) {
        void* q = (void*)p;
        p += (bytes + 255) & ~(size_t)255;
        return q;
    };
    float* dis   = (float*)alloc((size_t)N * 4);
    int*   cnt   = (int*)alloc((size_t)N * 4);
    int*   rowp  = (int*)alloc((size_t)(N + 1) * 4);
    int*   bsums = (int*)alloc(4096);
    int2*  csr   = (int2*)alloc((size_t)E * 8);
    float* Z     = (float*)alloc((size_t)N * HID * 4);
    unsigned short* xwb = (unsigned short*)alloc((size_t)N * HID * 2);
    float* zsum  = (float*)alloc((size_t)N * HID * 4);

    const int nb = (N + 1023) / 1024;

    // --- graph preprocessing: degrees + CSR by dst ---
    zero_i32<<<(N + 255) / 256, 256, 0, stream>>>(cnt, N);
    hist_kernel<<<(E + 255) / 256, 256, 0, stream>>>(dst, cnt, E);
    dis_kernel<<<(N + 255) / 256, 256, 0, stream>>>(cnt, dis, N);
    scan1<<<nb, 1024, 0, stream>>>(cnt, rowp, bsums, N);
    scan2<<<1, 64, 0, stream>>>(bsums, nb);
    scan3<<<nb, 1024, 0, stream>>>(rowp, bsums, N, E);
    zero_i32<<<(N + 255) / 256, 256, 0, stream>>>(cnt, N);
    scatter_kernel<<<(E + 255) / 256, 256, 0, stream>>>(src, dst, rowp, cnt, dis, csr, E);

    // --- Z1 = x@W1 + b1 ; zsum = 6*Z1 (fused epilogue) ---
    gemm_k128<128, 1, false, false><<<(N + 31) / 32, 256, 0, stream>>>(
        x, nullptr, W1, b1, Z, zsum, N, 1.f);

    // --- 4 GCN layers: conv-gemm writes bf16 xw; layers 2..4 also zsum += A ---
    gemm_k128<128, 0, false, true><<<(N + 31) / 32, 256, 0, stream>>>(
        Z, nullptr, convW, nullptr, xwb, nullptr, N, 1.f);
    spmm_kernel<<<(N + 15) / 16, 256, 0, stream>>>(xwb, rowp, csr, dis, convB, Z, N);
    for (int l = 1; l < NLAYERS; ++l) {
        gemm_k128<128, 2, false, true><<<(N + 31) / 32, 256, 0, stream>>>(
            Z, nullptr, convW + (size_t)l * HID * HID, nullptr, xwb, zsum, N, 1.f);
        spmm_kernel<<<(N + 15) / 16, 256, 0, stream>>>(
            xwb, rowp, csr, dis, convB + (size_t)l * HID, Z, N);
    }

    // --- out = 0.1*(zsum + Z5) @ W2 + b2 ---
    gemm_k128<64, 0, true, false><<<(N + 63) / 64, 256, 0, stream>>>(
        zsum, Z, W2, b2, (float*)d_out, nullptr, N, 0.1f);
}

// Round 3
// 705.401 us; speedup vs baseline: 1.7382x; 1.3693x over previous
//
#include <hip/hip_runtime.h>

#define HID 128
#define NLAYERS 4

typedef __attribute__((ext_vector_type(8))) short bf16x8;
typedef __attribute__((ext_vector_type(8))) unsigned short u16x8;
typedef __attribute__((ext_vector_type(4))) float f32x4;

static __device__ __forceinline__ float bf2f(unsigned short u) {
    return __uint_as_float(((unsigned)u) << 16);
}
static __device__ __forceinline__ unsigned short f2bf(float f) {
    unsigned u = __float_as_uint(f);
    return (unsigned short)((u + 0x7FFF + ((u >> 16) & 1)) >> 16);   // RNE
}

// ---------------- utility kernels ----------------

__global__ void zero_i32(int* p, int n) {
    int i = blockIdx.x * blockDim.x + threadIdx.x;
    if (i < n) p[i] = 0;
}

__global__ void hist_kernel(const int* __restrict__ dst, int* __restrict__ cnt, int E) {
    int e = blockIdx.x * blockDim.x + threadIdx.x;
    if (e < E) atomicAdd(&cnt[dst[e]], 1);
}

__global__ void dis_kernel(const int* __restrict__ cnt, float* __restrict__ dis, int n) {
    int i = blockIdx.x * blockDim.x + threadIdx.x;
    if (i < n) dis[i] = rsqrtf((float)cnt[i] + 1.0f);
}

__global__ void scan1(const int* __restrict__ cnt, int* __restrict__ rowp,
                      int* __restrict__ bsums, int n) {
    __shared__ int s[1024];
    int tid = threadIdx.x;
    int gid = blockIdx.x * 1024 + tid;
    int v = (gid < n) ? cnt[gid] : 0;
    s[tid] = v;
    __syncthreads();
    for (int off = 1; off < 1024; off <<= 1) {
        int t = (tid >= off) ? s[tid - off] : 0;
        __syncthreads();
        s[tid] += t;
        __syncthreads();
    }
    if (gid < n) rowp[gid] = s[tid] - v;   // exclusive
    if (tid == 1023) bsums[blockIdx.x] = s[1023];
}

__global__ void scan2(int* bsums, int nb) {
    if (threadIdx.x == 0 && blockIdx.x == 0) {
        int run = 0;
        for (int i = 0; i < nb; ++i) { int t = bsums[i]; bsums[i] = run; run += t; }
    }
}

__global__ void scan3(int* __restrict__ rowp, const int* __restrict__ bsums, int n, int E) {
    int gid = blockIdx.x * 1024 + threadIdx.x;
    if (gid < n) rowp[gid] += bsums[blockIdx.x];
    if (gid == 0) rowp[n] = E;
}

__global__ void scatter_kernel(const int* __restrict__ src, const int* __restrict__ dst,
                               const int* __restrict__ rowp, int* __restrict__ cursor,
                               const float* __restrict__ dis, int2* __restrict__ csr, int E) {
    int e = blockIdx.x * blockDim.x + threadIdx.x;
    if (e < E) {
        int d = dst[e], s = src[e];
        int pos = rowp[d] + atomicAdd(&cursor[d], 1);
        int2 v;
        v.x = s;
        v.y = __float_as_int(dis[s]);
        csr[pos] = v;
    }
}

// ---------------- weight prep: transpose + convert to bf16 ----------------
// Wt[n][k] = W[k][n].  Rows 0..127: W1; 128..639: convW (4 mats); 640..703: W2.

__global__ void wprep(const float* __restrict__ W1, const float* __restrict__ convW,
                      const float* __restrict__ W2, unsigned short* __restrict__ W1t,
                      unsigned short* __restrict__ convWt, unsigned short* __restrict__ W2t) {
    int r = blockIdx.x;
    int k = threadIdx.x;
    const float* src;
    unsigned short* dst;
    int ncols, n;
    if (r < 128) { src = W1; dst = W1t; n = r; ncols = 128; }
    else if (r < 640) {
        int l = (r - 128) >> 7; n = (r - 128) & 127;
        src = convW + (size_t)l * 16384; dst = convWt + (size_t)l * 16384; ncols = 128;
    } else { src = W2; dst = W2t; n = r - 640; ncols = 64; }
    dst[(size_t)n * 128 + k] = f2bf(src[(size_t)k * ncols + n]);
}

__global__ void xcast(const float* __restrict__ x, unsigned short* __restrict__ xb, int n8) {
    int i = blockIdx.x * blockDim.x + threadIdx.x;
    if (i >= n8) return;
    float4 v0 = *(const float4*)&x[(size_t)i * 8];
    float4 v1 = *(const float4*)&x[(size_t)i * 8 + 4];
    u16x8 o;
    o[0] = f2bf(v0.x); o[1] = f2bf(v0.y); o[2] = f2bf(v0.z); o[3] = f2bf(v0.w);
    o[4] = f2bf(v1.x); o[5] = f2bf(v1.y); o[6] = f2bf(v1.z); o[7] = f2bf(v1.w);
    *(u16x8*)&xb[(size_t)i * 8] = o;
}

// ---------------- MFMA GEMM: C[n,128] = A[n,128] @ Wt^T (+bias), all bf16 ----------------
// B (Wt) held fully in registers: 8 n-tiles x 4 k-steps x 4 VGPR = 128 VGPR/lane.
// 4 waves/block, 2 strips of 16 rows per wave -> 128 rows/block.
// Fragment layouts (16x16x32): A row=lane&15, k=(lane>>4)*8+j; B col=lane&15 (from Wt rows);
// C/D col=lane&15, row=(lane>>4)*4+reg  [m89-verified].

template <bool BIAS>
__global__ __launch_bounds__(256, 2) void gemm128_mfma(
    const unsigned short* __restrict__ A, const unsigned short* __restrict__ Bt,
    const float* __restrict__ bias, unsigned short* __restrict__ C, int nrows) {
    int wid = threadIdx.x >> 6, lane = threadIdx.x & 63;
    int l15 = lane & 15, l4 = lane >> 4;

    bf16x8 b[8][4];
#pragma unroll
    for (int nt = 0; nt < 8; ++nt)
#pragma unroll
        for (int ks = 0; ks < 4; ++ks)
            b[nt][ks] = *(const bf16x8*)&Bt[(size_t)(nt * 16 + l15) * 128 + ks * 32 + l4 * 8];
    float bb[8];
    if (BIAS) {
#pragma unroll
        for (int nt = 0; nt < 8; ++nt) bb[nt] = bias[nt * 16 + l15];
    }

    for (int s2 = 0; s2 < 2; ++s2) {
        int row0 = (blockIdx.x * 8 + wid * 2 + s2) * 16;
        if (row0 >= nrows) break;
        int ar = min(row0 + l15, nrows - 1);
        bf16x8 a[4];
#pragma unroll
        for (int ks = 0; ks < 4; ++ks)
            a[ks] = *(const bf16x8*)&A[(size_t)ar * 128 + ks * 32 + l4 * 8];
        f32x4 acc[8] = {};
#pragma unroll
        for (int ks = 0; ks < 4; ++ks)
#pragma unroll
            for (int nt = 0; nt < 8; ++nt)
                acc[nt] = __builtin_amdgcn_mfma_f32_16x16x32_bf16(a[ks], b[nt][ks], acc[nt], 0, 0, 0);
#pragma unroll
        for (int nt = 0; nt < 8; ++nt) {
            int col = nt * 16 + l15;
#pragma unroll
            for (int r = 0; r < 4; ++r) {
                int row = row0 + l4 * 4 + r;
                if (row < nrows) {
                    float v = acc[nt][r];
                    if (BIAS) v += bb[nt];
                    C[(size_t)row * 128 + col] = f2bf(v);
                }
            }
        }
    }
}

// ---------------- final GEMM: out = 0.6*Z1@W2 + 0.1*(Z2+Z3+Z4+Z5)@W2 + b2 ----------------

__global__ __launch_bounds__(256, 2) void gemm_final(
    const unsigned short* __restrict__ z0, const unsigned short* __restrict__ z1,
    const unsigned short* __restrict__ z2, const unsigned short* __restrict__ z3,
    const unsigned short* __restrict__ z4, const unsigned short* __restrict__ Bt,
    const float* __restrict__ bias, float* __restrict__ out, int nrows) {
    int wid = threadIdx.x >> 6, lane = threadIdx.x & 63;
    int l15 = lane & 15, l4 = lane >> 4;

    bf16x8 b[4][4];
#pragma unroll
    for (int nt = 0; nt < 4; ++nt)
#pragma unroll
        for (int ks = 0; ks < 4; ++ks)
            b[nt][ks] = *(const bf16x8*)&Bt[(size_t)(nt * 16 + l15) * 128 + ks * 32 + l4 * 8];
    float bb[4];
#pragma unroll
    for (int nt = 0; nt < 4; ++nt) bb[nt] = bias[nt * 16 + l15];

    const unsigned short* zs[5] = { z0, z1, z2, z3, z4 };

    for (int s2 = 0; s2 < 2; ++s2) {
        int row0 = (blockIdx.x * 8 + wid * 2 + s2) * 16;
        if (row0 >= nrows) break;
        int ar = min(row0 + l15, nrows - 1);
        bf16x8 a[5][4];
#pragma unroll
        for (int st = 0; st < 5; ++st)
#pragma unroll
            for (int ks = 0; ks < 4; ++ks)
                a[st][ks] = *(const bf16x8*)&zs[st][(size_t)ar * 128 + ks * 32 + l4 * 8];
        f32x4 acc0[4] = {};
        f32x4 acc1[4] = {};
#pragma unroll
        for (int st = 0; st < 5; ++st)
#pragma unroll
            for (int ks = 0; ks < 4; ++ks)
#pragma unroll
                for (int nt = 0; nt < 4; ++nt) {
                    if (st == 0)
                        acc0[nt] = __builtin_amdgcn_mfma_f32_16x16x32_bf16(a[0][ks], b[nt][ks], acc0[nt], 0, 0, 0);
                    else
                        acc1[nt] = __builtin_amdgcn_mfma_f32_16x16x32_bf16(a[st][ks], b[nt][ks], acc1[nt], 0, 0, 0);
                }
#pragma unroll
        for (int nt = 0; nt < 4; ++nt) {
            int col = nt * 16 + l15;
#pragma unroll
            for (int r = 0; r < 4; ++r) {
                int row = row0 + l4 * 4 + r;
                if (row < nrows)
                    out[(size_t)row * 64 + col] = 0.6f * acc0[nt][r] + 0.1f * acc1[nt][r] + bb[nt];
            }
        }
    }
}

// ---------------- fused SpMM(bf16 gather) + self-loop + bias + ReLU, bf16 out ----------------

__global__ __launch_bounds__(256) void spmm_kernel(
    const unsigned short* __restrict__ xwb, const int* __restrict__ rowp,
    const int2* __restrict__ csr, const float* __restrict__ dis,
    const float* __restrict__ bias, unsigned short* __restrict__ Z, int n) {
    int l = threadIdx.x & 15;
    int node = blockIdx.x * 16 + (threadIdx.x >> 4);
    if (node >= n) return;
    const u16x8* xw8 = (const u16x8*)xwb;   // 16 u16x8 per row

    float acc[8] = {};
    int beg = rowp[node], end = rowp[node + 1];
    int e = beg;
    for (; e + 1 < end; e += 2) {
        int2 s0 = csr[e];
        int2 s1 = csr[e + 1];
        u16x8 x0 = xw8[(size_t)s0.x * 16 + l];
        u16x8 x1 = xw8[(size_t)s1.x * 16 + l];
        float w0 = __int_as_float(s0.y);
        float w1 = __int_as_float(s1.y);
#pragma unroll
        for (int j = 0; j < 8; ++j) acc[j] = fmaf(w0, bf2f(x0[j]), acc[j]);
#pragma unroll
        for (int j = 0; j < 8; ++j) acc[j] = fmaf(w1, bf2f(x1[j]), acc[j]);
    }
    if (e < end) {
        int2 s0 = csr[e];
        u16x8 x0 = xw8[(size_t)s0.x * 16 + l];
        float w0 = __int_as_float(s0.y);
#pragma unroll
        for (int j = 0; j < 8; ++j) acc[j] = fmaf(w0, bf2f(x0[j]), acc[j]);
    }

    float d = dis[node];
    float d2 = d * d;
    u16x8 xs = xw8[(size_t)node * 16 + l];
    float4 b0 = *(const float4*)&bias[l * 8];
    float4 b1 = *(const float4*)&bias[l * 8 + 4];
    float bbv[8] = { b0.x, b0.y, b0.z, b0.w, b1.x, b1.y, b1.z, b1.w };
    u16x8 ov;
#pragma unroll
    for (int j = 0; j < 8; ++j)
        ov[j] = f2bf(fmaxf(fmaf(d, acc[j], fmaf(d2, bf2f(xs[j]), bbv[j])), 0.f));
    *(u16x8*)&Z[(size_t)node * HID + l * 8] = ov;
}

// ---------------- launcher ----------------

extern "C" void kernel_launch(void* const* d_in, const int* in_sizes, int n_in,
                              void* d_out, int out_size, void* d_ws, size_t ws_size,
                              hipStream_t stream) {
    const float* x     = (const float*)d_in[0];
    const int*   ei    = (const int*)d_in[1];
    const float* W1    = (const float*)d_in[2];
    const float* b1    = (const float*)d_in[3];
    const float* convW = (const float*)d_in[4];
    const float* convB = (const float*)d_in[5];
    const float* W2    = (const float*)d_in[6];
    const float* b2    = (const float*)d_in[7];

    const int N = in_sizes[0] / HID;
    const int E = in_sizes[1] / 2;
    const int* src = ei;
    const int* dst = ei + E;

    char* p = (char*)d_ws;
    auto alloc = [&](size_t bytes) {
        void* q = (void*)p;
        p += (bytes + 255) & ~(size_t)255;
        return q;
    };
    float* dis   = (float*)alloc((size_t)N * 4);
    int*   cnt   = (int*)alloc((size_t)N * 4);
    int*   rowp  = (int*)alloc((size_t)(N + 1) * 4);
    int*   bsums = (int*)alloc(4096);
    int2*  csr   = (int2*)alloc((size_t)E * 8);
    unsigned short* xb  = (unsigned short*)alloc((size_t)N * HID * 2);
    unsigned short* xw  = (unsigned short*)alloc((size_t)N * HID * 2);
    unsigned short* Zs[5];
    for (int i = 0; i < 4; ++i) Zs[i] = (unsigned short*)alloc((size_t)N * HID * 2);
    Zs[4] = xb;   // alias: xb dead after gemm1; Z5 written in layer 4 (after gemm1)
    unsigned short* W1t    = (unsigned short*)alloc(128 * 128 * 2);
    unsigned short* convWt = (unsigned short*)alloc((size_t)NLAYERS * 128 * 128 * 2);
    unsigned short* W2t    = (unsigned short*)alloc(64 * 128 * 2);

    const int nb = (N + 1023) / 1024;
    const int gemmBlocks = (N + 127) / 128;

    // --- weight prep + x cast ---
    wprep<<<704, 128, 0, stream>>>(W1, convW, W2, W1t, convWt, W2t);
    xcast<<<(N * 16 + 255) / 256, 256, 0, stream>>>(x, xb, N * 16);

    // --- graph preprocessing: degrees + CSR by dst ---
    zero_i32<<<(N + 255) / 256, 256, 0, stream>>>(cnt, N);
    hist_kernel<<<(E + 255) / 256, 256, 0, stream>>>(dst, cnt, E);
    dis_kernel<<<(N + 255) / 256, 256, 0, stream>>>(cnt, dis, N);
    scan1<<<nb, 1024, 0, stream>>>(cnt, rowp, bsums, N);
    scan2<<<1, 64, 0, stream>>>(bsums, nb);
    scan3<<<nb, 1024, 0, stream>>>(rowp, bsums, N, E);
    zero_i32<<<(N + 255) / 256, 256, 0, stream>>>(cnt, N);
    scatter_kernel<<<(E + 255) / 256, 256, 0, stream>>>(src, dst, rowp, cnt, dis, csr, E);

    // --- Z1 = bf16(x @ W1 + b1) ---
    gemm128_mfma<true><<<gemmBlocks, 256, 0, stream>>>(xb, W1t, b1, Zs[0], N);

    // --- 4 GCN layers ---
    for (int l = 0; l < NLAYERS; ++l) {
        gemm128_mfma<false><<<gemmBlocks, 256, 0, stream>>>(
            Zs[l], convWt + (size_t)l * 16384, nullptr, xw, N);
        spmm_kernel<<<(N + 15) / 16, 256, 0, stream>>>(
            xw, rowp, csr, dis, convB + (size_t)l * HID, Zs[l + 1], N);
    }

    // --- out = 0.6*Z1@W2 + 0.1*(Z2+..+Z5)@W2 + b2 ---
    gemm_final<<<gemmBlocks, 256, 0, stream>>>(
        Zs[0], Zs[1], Zs[2], Zs[3], Zs[4], W2t, b2, (float*)d_out, N);
}

// Round 4
// 666.746 us; speedup vs baseline: 1.8389x; 1.0580x over previous
//
#include <hip/hip_runtime.h>

#define HID 128
#define NLAYERS 4
#define MAXBUCK 1600     // >= ceil(100000/64)=1563
#define CHUNK 16384

typedef __attribute__((ext_vector_type(8))) short bf16x8;
typedef __attribute__((ext_vector_type(8))) unsigned short u16x8;
typedef __attribute__((ext_vector_type(4))) float f32x4;

static __device__ __forceinline__ float bf2f(unsigned short u) {
    return __uint_as_float(((unsigned)u) << 16);
}
static __device__ __forceinline__ unsigned short f2bf(float f) {
    unsigned u = __float_as_uint(f);
    return (unsigned short)((u + 0x7FFF + ((u >> 16) & 1)) >> 16);   // RNE
}

// ---------------- preprocessing: deterministic two-level counting sort ----------------

// per-chunk LDS histogram over coarse buckets (64 dst nodes each); no global atomics
__global__ __launch_bounds__(256) void bin1(const int* __restrict__ dst,
                                            int* __restrict__ cnt2d, int E, int nbuck) {
    __shared__ int h[MAXBUCK];
    int tid = threadIdx.x;
    for (int i = tid; i < nbuck; i += 256) h[i] = 0;
    __syncthreads();
    int e0 = blockIdx.x * CHUNK;
    int e1 = min(e0 + CHUNK, E);
    for (int e = e0 + tid; e < e1; e += 256) atomicAdd(&h[dst[e] >> 6], 1);
    __syncthreads();
    for (int i = tid; i < nbuck; i += 256)
        cnt2d[(size_t)blockIdx.x * nbuck + i] = h[i];
}

// per-bucket exclusive prefix over chunks (in place); column sums out
__global__ void colscan(int* __restrict__ cnt2d, int* __restrict__ colsum,
                        int nchunks, int nbuck) {
    int b = blockIdx.x * blockDim.x + threadIdx.x;
    if (b >= nbuck) return;
    int run = 0;
    for (int c = 0; c < nchunks; ++c) {
        size_t idx = (size_t)c * nbuck + b;
        int v = cnt2d[idx];
        cnt2d[idx] = run;
        run += v;
    }
    colsum[b] = run;
}

// exclusive scan of colsum -> base[0..nbuck] (base[b+1] = incl prefix)
__global__ __launch_bounds__(256) void basescan(const int* __restrict__ colsum,
                                                int* __restrict__ base, int nbuck) {
    __shared__ int part[256];
    int tid = threadIdx.x;
    const int per = 7;   // 256*7=1792 >= MAXBUCK
    int loc[per];
    int run = 0;
    for (int i = 0; i < per; ++i) {
        int idx = tid * per + i;
        int v = (idx < nbuck) ? colsum[idx] : 0;
        run += v;
        loc[i] = run;
    }
    part[tid] = run;
    __syncthreads();
    for (int off = 1; off < 256; off <<= 1) {
        int t = (tid >= off) ? part[tid - off] : 0;
        __syncthreads();
        part[tid] += t;
        __syncthreads();
    }
    int prev = tid ? part[tid - 1] : 0;
    if (tid == 0) base[0] = 0;
    for (int i = 0; i < per; ++i) {
        int idx = tid * per + i;
        if (idx < nbuck) base[idx + 1] = prev + loc[i];
    }
}

// scatter edges into coarse-bucket regions, packed src | (dst&63)<<20
__global__ __launch_bounds__(256) void bin2(const int* __restrict__ src, const int* __restrict__ dst,
                                            const int* __restrict__ cnt2d, const int* __restrict__ base,
                                            unsigned* __restrict__ ecoarse, int E, int nbuck) {
    __shared__ int cur[MAXBUCK];
    int tid = threadIdx.x;
    for (int i = tid; i < nbuck; i += 256)
        cur[i] = base[i] + cnt2d[(size_t)blockIdx.x * nbuck + i];
    __syncthreads();
    int e0 = blockIdx.x * CHUNK;
    int e1 = min(e0 + CHUNK, E);
    for (int e = e0 + tid; e < e1; e += 256) {
        int d = dst[e];
        int b = d >> 6;
        int pos = atomicAdd(&cur[b], 1);
        ecoarse[pos] = (unsigned)src[e] | ((unsigned)(d & 63) << 20);
    }
}

// per-bucket degree count (sequential reads) -> dis = rsqrt(deg+1)
__global__ __launch_bounds__(64) void degdis(const unsigned* __restrict__ ecoarse,
                                             const int* __restrict__ base,
                                             float* __restrict__ dis, int N) {
    __shared__ int cnt[64];
    int b = blockIdx.x, t = threadIdx.x;
    cnt[t] = 0;
    __syncthreads();
    int s = base[b], e = base[b + 1];
    for (int i = s + t; i < e; i += 64) atomicAdd(&cnt[ecoarse[i] >> 20], 1);
    __syncthreads();
    int node = b * 64 + t;
    if (node < N) dis[node] = rsqrtf((float)cnt[t] + 1.0f);
}

// per-bucket LDS counting sort by dlocal -> exact CSR (src, w) + rowp
__global__ __launch_bounds__(256) void finesort(const unsigned* __restrict__ ecoarse,
                                                const int* __restrict__ base,
                                                const float* __restrict__ dis,
                                                int2* __restrict__ csr, int* __restrict__ rowp,
                                                int N, int E) {
    __shared__ int h[64], off[64];
    int b = blockIdx.x, tid = threadIdx.x;
    if (tid < 64) h[tid] = 0;
    __syncthreads();
    int s = base[b], e = base[b + 1];
    for (int i = s + tid; i < e; i += 256) atomicAdd(&h[ecoarse[i] >> 20], 1);
    __syncthreads();
    if (tid == 0) {
        int run = 0;
        for (int i = 0; i < 64; ++i) { off[i] = run; run += h[i]; }
    }
    __syncthreads();
    int node = b * 64 + tid;
    if (tid < 64 && node < N) rowp[node] = s + off[tid];
    if (b == 0 && tid == 0) rowp[N] = E;
    if (tid < 64) h[tid] = off[tid];   // reuse as cursors
    __syncthreads();
    for (int i = s + tid; i < e; i += 256) {
        unsigned v = ecoarse[i];
        int srcn = v & 0xFFFFF;
        int dl = v >> 20;
        int pos = atomicAdd(&h[dl], 1);
        int2 o;
        o.x = srcn;
        o.y = __float_as_int(dis[srcn] * dis[b * 64 + dl]);
        csr[s + pos] = o;
    }
}

// ---------------- weight prep: transpose + convert to bf16 ----------------

__global__ void wprep(const float* __restrict__ W1, const float* __restrict__ convW,
                      const float* __restrict__ W2, unsigned short* __restrict__ W1t,
                      unsigned short* __restrict__ convWt, unsigned short* __restrict__ W2t) {
    int r = blockIdx.x;
    int k = threadIdx.x;
    const float* src;
    unsigned short* dst;
    int ncols, n;
    if (r < 128) { src = W1; dst = W1t; n = r; ncols = 128; }
    else if (r < 640) {
        int l = (r - 128) >> 7; n = (r - 128) & 127;
        src = convW + (size_t)l * 16384; dst = convWt + (size_t)l * 16384; ncols = 128;
    } else { src = W2; dst = W2t; n = r - 640; ncols = 64; }
    dst[(size_t)n * 128 + k] = f2bf(src[(size_t)k * ncols + n]);
}

__global__ void xcast(const float* __restrict__ x, unsigned short* __restrict__ xb, int n8) {
    int i = blockIdx.x * blockDim.x + threadIdx.x;
    if (i >= n8) return;
    float4 v0 = *(const float4*)&x[(size_t)i * 8];
    float4 v1 = *(const float4*)&x[(size_t)i * 8 + 4];
    u16x8 o;
    o[0] = f2bf(v0.x); o[1] = f2bf(v0.y); o[2] = f2bf(v0.z); o[3] = f2bf(v0.w);
    o[4] = f2bf(v1.x); o[5] = f2bf(v1.y); o[6] = f2bf(v1.z); o[7] = f2bf(v1.w);
    *(u16x8*)&xb[(size_t)i * 8] = o;
}

// ---------------- MFMA GEMM: C[n,128] = A[n,128] @ Wt^T (+bias), all bf16 ----------------

template <bool BIAS>
__global__ __launch_bounds__(256, 2) void gemm128_mfma(
    const unsigned short* __restrict__ A, const unsigned short* __restrict__ Bt,
    const float* __restrict__ bias, unsigned short* __restrict__ C, int nrows) {
    int wid = threadIdx.x >> 6, lane = threadIdx.x & 63;
    int l15 = lane & 15, l4 = lane >> 4;

    bf16x8 b[8][4];
#pragma unroll
    for (int nt = 0; nt < 8; ++nt)
#pragma unroll
        for (int ks = 0; ks < 4; ++ks)
            b[nt][ks] = *(const bf16x8*)&Bt[(size_t)(nt * 16 + l15) * 128 + ks * 32 + l4 * 8];
    float bb[8];
    if (BIAS) {
#pragma unroll
        for (int nt = 0; nt < 8; ++nt) bb[nt] = bias[nt * 16 + l15];
    }

    for (int s2 = 0; s2 < 2; ++s2) {
        int row0 = (blockIdx.x * 8 + wid * 2 + s2) * 16;
        if (row0 >= nrows) break;
        int ar = min(row0 + l15, nrows - 1);
        bf16x8 a[4];
#pragma unroll
        for (int ks = 0; ks < 4; ++ks)
            a[ks] = *(const bf16x8*)&A[(size_t)ar * 128 + ks * 32 + l4 * 8];
        f32x4 acc[8] = {};
#pragma unroll
        for (int ks = 0; ks < 4; ++ks)
#pragma unroll
            for (int nt = 0; nt < 8; ++nt)
                acc[nt] = __builtin_amdgcn_mfma_f32_16x16x32_bf16(a[ks], b[nt][ks], acc[nt], 0, 0, 0);
#pragma unroll
        for (int nt = 0; nt < 8; ++nt) {
            int col = nt * 16 + l15;
#pragma unroll
            for (int r = 0; r < 4; ++r) {
                int row = row0 + l4 * 4 + r;
                if (row < nrows) {
                    float v = acc[nt][r];
                    if (BIAS) v += bb[nt];
                    C[(size_t)row * 128 + col] = f2bf(v);
                }
            }
        }
    }
}

// ---------------- final GEMM: out = 0.6*Z1@W2 + 0.1*(Z2+Z3+Z4+Z5)@W2 + b2 ----------------

__global__ __launch_bounds__(256, 2) void gemm_final(
    const unsigned short* __restrict__ z0, const unsigned short* __restrict__ z1,
    const unsigned short* __restrict__ z2, const unsigned short* __restrict__ z3,
    const unsigned short* __restrict__ z4, const unsigned short* __restrict__ Bt,
    const float* __restrict__ bias, float* __restrict__ out, int nrows) {
    int wid = threadIdx.x >> 6, lane = threadIdx.x & 63;
    int l15 = lane & 15, l4 = lane >> 4;

    bf16x8 b[4][4];
#pragma unroll
    for (int nt = 0; nt < 4; ++nt)
#pragma unroll
        for (int ks = 0; ks < 4; ++ks)
            b[nt][ks] = *(const bf16x8*)&Bt[(size_t)(nt * 16 + l15) * 128 + ks * 32 + l4 * 8];
    float bb[4];
#pragma unroll
    for (int nt = 0; nt < 4; ++nt) bb[nt] = bias[nt * 16 + l15];

    const unsigned short* zs[5] = { z0, z1, z2, z3, z4 };

    for (int s2 = 0; s2 < 2; ++s2) {
        int row0 = (blockIdx.x * 8 + wid * 2 + s2) * 16;
        if (row0 >= nrows) break;
        int ar = min(row0 + l15, nrows - 1);
        bf16x8 a[5][4];
#pragma unroll
        for (int st = 0; st < 5; ++st)
#pragma unroll
            for (int ks = 0; ks < 4; ++ks)
                a[st][ks] = *(const bf16x8*)&zs[st][(size_t)ar * 128 + ks * 32 + l4 * 8];
        f32x4 acc0[4] = {};
        f32x4 acc1[4] = {};
#pragma unroll
        for (int st = 0; st < 5; ++st)
#pragma unroll
            for (int ks = 0; ks < 4; ++ks)
#pragma unroll
                for (int nt = 0; nt < 4; ++nt) {
                    if (st == 0)
                        acc0[nt] = __builtin_amdgcn_mfma_f32_16x16x32_bf16(a[0][ks], b[nt][ks], acc0[nt], 0, 0, 0);
                    else
                        acc1[nt] = __builtin_amdgcn_mfma_f32_16x16x32_bf16(a[st][ks], b[nt][ks], acc1[nt], 0, 0, 0);
                }
#pragma unroll
        for (int nt = 0; nt < 4; ++nt) {
            int col = nt * 16 + l15;
#pragma unroll
            for (int r = 0; r < 4; ++r) {
                int row = row0 + l4 * 4 + r;
                if (row < nrows)
                    out[(size_t)row * 64 + col] = 0.6f * acc0[nt][r] + 0.1f * acc1[nt][r] + bb[nt];
            }
        }
    }
}

// ---------------- fused SpMM(bf16 gather) + self-loop + bias + ReLU, bf16 out ----------------
// 16 lanes/node, ushort8 per lane; 4-deep gather pipeline (norm pre-folded into w).

__global__ __launch_bounds__(256) void spmm_kernel(
    const unsigned short* __restrict__ xwb, const int* __restrict__ rowp,
    const int2* __restrict__ csr, const float* __restrict__ dis,
    const float* __restrict__ bias, unsigned short* __restrict__ Z, int n) {
    int l = threadIdx.x & 15;
    int node = blockIdx.x * 16 + (threadIdx.x >> 4);
    if (node >= n) return;
    const u16x8* xw8 = (const u16x8*)xwb;

    float acc[8] = {};
    int beg = rowp[node], end = rowp[node + 1];
    int e = beg;
    for (; e + 4 <= end; e += 4) {
        int2 s0 = csr[e];
        int2 s1 = csr[e + 1];
        int2 s2 = csr[e + 2];
        int2 s3 = csr[e + 3];
        u16x8 x0 = xw8[(size_t)s0.x * 16 + l];
        u16x8 x1 = xw8[(size_t)s1.x * 16 + l];
        u16x8 x2 = xw8[(size_t)s2.x * 16 + l];
        u16x8 x3 = xw8[(size_t)s3.x * 16 + l];
        float w0 = __int_as_float(s0.y);
        float w1 = __int_as_float(s1.y);
        float w2 = __int_as_float(s2.y);
        float w3 = __int_as_float(s3.y);
#pragma unroll
        for (int j = 0; j < 8; ++j) {
            acc[j] = fmaf(w0, bf2f(x0[j]), acc[j]);
            acc[j] = fmaf(w1, bf2f(x1[j]), acc[j]);
            acc[j] = fmaf(w2, bf2f(x2[j]), acc[j]);
            acc[j] = fmaf(w3, bf2f(x3[j]), acc[j]);
        }
    }
    for (; e < end; ++e) {
        int2 s0 = csr[e];
        u16x8 x0 = xw8[(size_t)s0.x * 16 + l];
        float w0 = __int_as_float(s0.y);
#pragma unroll
        for (int j = 0; j < 8; ++j) acc[j] = fmaf(w0, bf2f(x0[j]), acc[j]);
    }

    float d = dis[node];
    float d2 = d * d;
    u16x8 xs = xw8[(size_t)node * 16 + l];
    float4 b0 = *(const float4*)&bias[l * 8];
    float4 b1 = *(const float4*)&bias[l * 8 + 4];
    float bbv[8] = { b0.x, b0.y, b0.z, b0.w, b1.x, b1.y, b1.z, b1.w };
    u16x8 ov;
#pragma unroll
    for (int j = 0; j < 8; ++j)
        ov[j] = f2bf(fmaxf(acc[j] + fmaf(d2, bf2f(xs[j]), bbv[j]), 0.f));
    *(u16x8*)&Z[(size_t)node * HID + l * 8] = ov;
}

// ---------------- launcher ----------------

extern "C" void kernel_launch(void* const* d_in, const int* in_sizes, int n_in,
                              void* d_out, int out_size, void* d_ws, size_t ws_size,
                              hipStream_t stream) {
    const float* x     = (const float*)d_in[0];
    const int*   ei    = (const int*)d_in[1];
    const float* W1    = (const float*)d_in[2];
    const float* b1    = (const float*)d_in[3];
    const float* convW = (const float*)d_in[4];
    const float* convB = (const float*)d_in[5];
    const float* W2    = (const float*)d_in[6];
    const float* b2    = (const float*)d_in[7];

    const int N = in_sizes[0] / HID;
    const int E = in_sizes[1] / 2;
    const int* src = ei;
    const int* dst = ei + E;
    const int nbuck = (N + 63) / 64;
    const int nchunks = (E + CHUNK - 1) / CHUNK;

    char* p = (char*)d_ws;
    auto alloc = [&](size_t bytes) {
        void* q = (void*)p;
        p += (bytes + 255) & ~(size_t)255;
        return q;
    };
    float* dis      = (float*)alloc((size_t)N * 4);
    int*   rowp     = (int*)alloc((size_t)(N + 1) * 4);
    int*   base     = (int*)alloc((size_t)(nbuck + 1) * 4);
    int*   colsum   = (int*)alloc((size_t)nbuck * 4);
    int*   cnt2d    = (int*)alloc((size_t)nchunks * nbuck * 4);
    unsigned* ecoarse = (unsigned*)alloc((size_t)E * 4);
    int2*  csr      = (int2*)alloc((size_t)E * 8);
    unsigned short* xb = (unsigned short*)alloc((size_t)N * HID * 2);
    unsigned short* xw = (unsigned short*)alloc((size_t)N * HID * 2);
    unsigned short* Zs[5];
    for (int i = 0; i < 4; ++i) Zs[i] = (unsigned short*)alloc((size_t)N * HID * 2);
    Zs[4] = xb;   // alias: xb dead after gemm1
    unsigned short* W1t    = (unsigned short*)alloc(128 * 128 * 2);
    unsigned short* convWt = (unsigned short*)alloc((size_t)NLAYERS * 128 * 128 * 2);
    unsigned short* W2t    = (unsigned short*)alloc(64 * 128 * 2);

    const int gemmBlocks = (N + 127) / 128;

    // --- weight prep + x cast ---
    wprep<<<704, 128, 0, stream>>>(W1, convW, W2, W1t, convWt, W2t);
    xcast<<<(N * 16 + 255) / 256, 256, 0, stream>>>(x, xb, N * 16);

    // --- graph preprocessing: two-level deterministic counting sort ---
    bin1<<<nchunks, 256, 0, stream>>>(dst, cnt2d, E, nbuck);
    colscan<<<(nbuck + 255) / 256, 256, 0, stream>>>(cnt2d, colsum, nchunks, nbuck);
    basescan<<<1, 256, 0, stream>>>(colsum, base, nbuck);
    bin2<<<nchunks, 256, 0, stream>>>(src, dst, cnt2d, base, ecoarse, E, nbuck);
    degdis<<<nbuck, 64, 0, stream>>>(ecoarse, base, dis, N);
    finesort<<<nbuck, 256, 0, stream>>>(ecoarse, base, dis, csr, rowp, N, E);

    // --- Z1 = bf16(x @ W1 + b1) ---
    gemm128_mfma<true><<<gemmBlocks, 256, 0, stream>>>(xb, W1t, b1, Zs[0], N);

    // --- 4 GCN layers ---
    for (int l = 0; l < NLAYERS; ++l) {
        gemm128_mfma<false><<<gemmBlocks, 256, 0, stream>>>(
            Zs[l], convWt + (size_t)l * 16384, nullptr, xw, N);
        spmm_kernel<<<(N + 15) / 16, 256, 0, stream>>>(
            xw, rowp, csr, dis, convB + (size_t)l * HID, Zs[l + 1], N);
    }

    // --- out = 0.6*Z1@W2 + 0.1*(Z2+..+Z5)@W2 + b2 ---
    gemm_final<<<gemmBlocks, 256, 0, stream>>>(
        Zs[0], Zs[1], Zs[2], Zs[3], Zs[4], W2t, b2, (float*)d_out, N);
}